// Round 4
// baseline (477.089 us; speedup 1.0000x reference)
//
#include <hip/hip_runtime.h>
#include <float.h>
#include <limits.h>
#include <math.h>

namespace {

constexpr int NB = 8;
constexpr int SL = 2048;
constexpr int DIM = 128;
constexpr int PP = 64;
constexpr int KK = 64;
constexpr int ROWS = 64;
constexpr int CTILE = 64;
constexpr int NSTRIP = SL / ROWS;        // 32
constexpr int CSPLIT = 8;
constexpr int NSLOT = NSTRIP * CSPLIT;   // 256 slots per batch
constexpr int CAP = 512;                 // candidate buffer (expected ~21/block)
constexpr float MARGIN = 4e-3f;          // >> 40x worst-case fp32 dot error

__device__ __forceinline__ bool cgt64(double v1, int i1, double v2, int i2) {
  return (v1 > v2) || (v1 == v2 && i1 < i2);
}
__device__ __forceinline__ bool cgt32(float v1, int i1, float v2, int i2) {
  return (v1 > v2) || (v1 == v2 && i1 < i2);
}

// Canonicalize mask (int32 words or raw bytes) + per-batch compaction.
__global__ __launch_bounds__(256) void compact_kernel(
    const void* __restrict__ mask_raw, int* __restrict__ pos, int* __restrict__ cnt) {
  const int b = blockIdx.x;
  const int tid = threadIdx.x;
  const int lane = tid & 63, wid = tid >> 6;
  __shared__ int bytemode;
  __shared__ int wsum[4];
  if (tid == 0) bytemode = 0;
  __syncthreads();
  const unsigned char* allb = (const unsigned char*)mask_raw;
  // dtype probe on first 512 bytes: int32-bool has zero at every t%4!=0
  int local = 0;
  for (int t = tid; t < 512; t += 256)
    if ((t & 3) != 0 && allb[t] != 0) local = 1;
  if (local) atomicOr(&bytemode, 1);
  __syncthreads();
  int f[8]; int c = 0;
  const int base = tid * 8;
  if (bytemode) {
    const unsigned char* p = allb + (size_t)b * SL;
    for (int j = 0; j < 8; ++j) { f[j] = p[base + j] ? 1 : 0; c += f[j]; }
  } else {
    const int* p = (const int*)mask_raw + (size_t)b * SL;
    for (int j = 0; j < 8; ++j) { f[j] = p[base + j] ? 1 : 0; c += f[j]; }
  }
  int incl = c;
  for (int off = 1; off < 64; off <<= 1) {
    int t = __shfl_up(incl, off);
    if (lane >= off) incl += t;
  }
  if (lane == 63) wsum[wid] = incl;
  __syncthreads();
  int woff = 0;
  for (int w = 0; w < wid; ++w) woff += wsum[w];
  int k = woff + incl - c;
  for (int j = 0; j < 8; ++j)
    if (f[j]) pos[b * SL + (k++)] = base + j;
  if (tid == 255) cnt[b] = k;
}

// Q = x@Wq+bq, K = x@Wk+bk. fp64 accumulation (8 indep chains), fp32 store.
// 8 rows/block, thread = (row, p-pair). float2 weight loads.
__global__ __launch_bounds__(256) void proj_kernel(
    const float* __restrict__ x,
    const float* __restrict__ Wq, const float* __restrict__ bq,
    const float* __restrict__ Wk, const float* __restrict__ bk,
    float* __restrict__ Q, float* __restrict__ K) {
  __shared__ float sx[8 * DIM];
  const int row0 = blockIdx.x * 8;
  const int tid = threadIdx.x;
  for (int t = tid; t < 8 * DIM; t += 256) sx[t] = x[(size_t)row0 * DIM + t];
  __syncthreads();
  const int r = tid >> 5;
  const int pp = (tid & 31) * 2;
  double aq0 = 0, aq1 = 0, ak0 = 0, ak1 = 0;
  double cq0 = 0, cq1 = 0, ck0 = 0, ck1 = 0;
  const float* xr = &sx[r * DIM];
  for (int d = 0; d < DIM; d += 2) {
    const double x0 = (double)xr[d], x1 = (double)xr[d + 1];
    const float2 wq0 = *(const float2*)&Wq[d * PP + pp];
    const float2 wq1 = *(const float2*)&Wq[(d + 1) * PP + pp];
    const float2 wk0 = *(const float2*)&Wk[d * PP + pp];
    const float2 wk1 = *(const float2*)&Wk[(d + 1) * PP + pp];
    aq0 += x0 * (double)wq0.x; aq1 += x0 * (double)wq0.y;
    cq0 += x1 * (double)wq1.x; cq1 += x1 * (double)wq1.y;
    ak0 += x0 * (double)wk0.x; ak1 += x0 * (double)wk0.y;
    ck0 += x1 * (double)wk1.x; ck1 += x1 * (double)wk1.y;
  }
  const size_t o = ((size_t)row0 + r) * PP + pp;
  Q[o]     = (float)(aq0 + cq0 + (double)bq[pp]);
  Q[o + 1] = (float)(aq1 + cq1 + (double)bq[pp + 1]);
  K[o]     = (float)(ak0 + ck0 + (double)bk[pp]);
  K[o + 1] = (float)(ak1 + ck1 + (double)bk[pp + 1]);
}

// Safe threshold: 64th of 256 per-thread maxima over 128x128-valid subset.
// Any subset 64th is a lower bound on the global 64th.
__global__ __launch_bounds__(256, 2) void t0_kernel(
    const float* __restrict__ Q, const float* __restrict__ K,
    const int* __restrict__ pos, const int* __restrict__ cnt,
    float* __restrict__ T0) {
  __shared__ __align__(16) float sq[128 * 68];
  __shared__ __align__(16) float sk[128 * 68];
  __shared__ float smax[256];
  const int b = blockIdx.x;
  const int tid = threadIdx.x;
  const int nv = cnt[b];
  const int nr = nv < 128 ? nv : 128;
  for (int t = tid; t < 128 * 16; t += 256) {
    const int row = t >> 4, p4 = t & 15;
    float4 qv = make_float4(0.f, 0.f, 0.f, 0.f), kv = qv;
    if (row < nr) {
      const int g = pos[b * SL + row];
      qv = *(const float4*)(Q + ((size_t)b * SL + g) * PP + p4 * 4);
      kv = *(const float4*)(K + ((size_t)b * SL + g) * PP + p4 * 4);
    }
    *(float4*)&sq[row * 68 + p4 * 4] = qv;
    *(float4*)&sk[row * 68 + p4 * 4] = kv;
  }
  __syncthreads();
  const int ry = tid & 15, cy = tid >> 4;
  float acc[8][8] = {};
  for (int p4 = 0; p4 < 16; ++p4) {
    float4 qv[8], kv[8];
#pragma unroll
    for (int i = 0; i < 8; ++i) qv[i] = *(const float4*)&sq[(ry + 16 * i) * 68 + p4 * 4];
#pragma unroll
    for (int j = 0; j < 8; ++j) kv[j] = *(const float4*)&sk[(cy + 16 * j) * 68 + p4 * 4];
#pragma unroll
    for (int i = 0; i < 8; ++i)
#pragma unroll
      for (int j = 0; j < 8; ++j) {
        acc[i][j] = fmaf(qv[i].x, kv[j].x, acc[i][j]);
        acc[i][j] = fmaf(qv[i].y, kv[j].y, acc[i][j]);
        acc[i][j] = fmaf(qv[i].z, kv[j].z, acc[i][j]);
        acc[i][j] = fmaf(qv[i].w, kv[j].w, acc[i][j]);
      }
  }
  float lmax = -FLT_MAX;
  for (int i = 0; i < 8; ++i)
    for (int j = 0; j < 8; ++j)
      if ((ry + 16 * i) < nr && (cy + 16 * j) < nr)
        lmax = fmaxf(lmax, acc[i][j] * 0.125f);
  smax[tid] = lmax;
  __syncthreads();
  // bitonic-256 descending on values
  for (int k2 = 2; k2 <= 256; k2 <<= 1)
    for (int j2 = k2 >> 1; j2 >= 1; j2 >>= 1) {
      if (tid < 128) {
        const int i = ((tid & ~(j2 - 1)) << 1) | (tid & (j2 - 1));
        const int p = i | j2;
        const bool desc = ((i & k2) == 0);
        const float vi = smax[i], vp = smax[p];
        const bool sw = desc ? (vp > vi) : (vi > vp);
        if (sw) { smax[i] = vp; smax[p] = vi; }
      }
      __syncthreads();
    }
  if (tid == 0) T0[b] = (smax[KK - 1] > -FLT_MAX) ? smax[KK - 1] - MARGIN : -FLT_MAX;
}

// Per (batch, 64-row strip, col eighth): fp32 scores with conflict-free
// 4x4 strided micro-tile, wave-granular thresholded emission, fp64 refine,
// bitonic-512 exact sort, top-64 out (sorted desc by (val, idx)).
__global__ __launch_bounds__(256, 4) void score_kernel(
    const float* __restrict__ Q, const float* __restrict__ K,
    const int* __restrict__ pos, const int* __restrict__ cnt,
    const float* __restrict__ T0,
    double* __restrict__ chunk_val, int* __restrict__ chunk_idx) {
  __shared__ __align__(16) float sQ[64 * 68];   // [row][17 float4] — aliased by rval later
  __shared__ __align__(16) float sK[64 * 68];
  __shared__ float cval[CAP];
  __shared__ int cidx[CAP];
  __shared__ int spos_r[ROWS], spos_c[CTILE];
  __shared__ int cnt_sh, ovf, mcnt;
  __shared__ float thresh;

  const int b = blockIdx.z, strip = blockIdx.x, colq = blockIdx.y;
  const int tid = threadIdx.x, lane = tid & 63;
  const int nv = cnt[b];
  const int slot = (b * NSTRIP + strip) * CSPLIT + colq;
  const int r0 = strip * ROWS;
  const int per = (nv + CSPLIT - 1) / CSPLIT;
  const int cbeg = colq * per;
  const int cend = min(cbeg + per, nv);
  double* chv = chunk_val + (size_t)slot * KK;
  int* chi = chunk_idx + (size_t)slot * KK;
  if (r0 >= nv || cbeg >= cend) {
    if (tid < KK) { chv[tid] = -DBL_MAX; chi[tid] = INT_MAX; }
    return;
  }
  const int nrows = min(ROWS, nv - r0);
  if (tid < ROWS) spos_r[tid] = (tid < nrows) ? pos[b * SL + r0 + tid] : 0;
  for (int t = tid; t < 64 * 16; t += 256) {
    const int row = t >> 4, p4 = t & 15;
    float4 v = make_float4(0.f, 0.f, 0.f, 0.f);
    if (row < nrows) {
      const int g = pos[b * SL + r0 + row];
      v = *(const float4*)(Q + ((size_t)b * SL + g) * PP + p4 * 4);
    }
    *(float4*)&sQ[row * 68 + p4 * 4] = v;
  }
  if (tid == 0) { cnt_sh = 0; ovf = 0; thresh = T0[b]; }
  __syncthreads();

  const int ry = tid & 15, cy = tid >> 4;   // rows ry+16i, cols cy+16j

  for (int c0 = cbeg; c0 < cend; c0 += CTILE) {
    const int ncols = min(CTILE, cend - c0);
    if (tid < CTILE) spos_c[tid] = (tid < ncols) ? pos[b * SL + c0 + tid] : 0;
    for (int t = tid; t < 64 * 16; t += 256) {
      const int col = t >> 4, p4 = t & 15;
      float4 v = make_float4(0.f, 0.f, 0.f, 0.f);
      if (col < ncols) {
        const int g = pos[b * SL + c0 + col];
        v = *(const float4*)(K + ((size_t)b * SL + g) * PP + p4 * 4);
      }
      *(float4*)&sK[col * 68 + p4 * 4] = v;
    }
    __syncthreads();

    float acc[4][4] = {};
#pragma unroll
    for (int p4 = 0; p4 < 16; ++p4) {
      float4 qv[4], kv[4];
#pragma unroll
      for (int i = 0; i < 4; ++i) qv[i] = *(const float4*)&sQ[(ry + 16 * i) * 68 + p4 * 4];
#pragma unroll
      for (int j = 0; j < 4; ++j) kv[j] = *(const float4*)&sK[(cy + 16 * j) * 68 + p4 * 4];
#pragma unroll
      for (int i = 0; i < 4; ++i)
#pragma unroll
        for (int j = 0; j < 4; ++j) {
          acc[i][j] = fmaf(qv[i].x, kv[j].x, acc[i][j]);
          acc[i][j] = fmaf(qv[i].y, kv[j].y, acc[i][j]);
          acc[i][j] = fmaf(qv[i].z, kv[j].z, acc[i][j]);
          acc[i][j] = fmaf(qv[i].w, kv[j].w, acc[i][j]);
        }
    }

    // wave-granular all-or-nothing emission; overflow -> compact + retry
    bool pushed = false;
    for (int attempt = 0; attempt < 8; ++attempt) {
      const float th = thresh;
      int nloc = 0;
#pragma unroll
      for (int i = 0; i < 4; ++i)
#pragma unroll
        for (int j = 0; j < 4; ++j)
          if ((ry + 16 * i) < nrows && (cy + 16 * j) < ncols &&
              acc[i][j] * 0.125f >= th)
            nloc++;
      int incl = nloc;
      for (int off = 1; off < 64; off <<= 1) {
        int t2 = __shfl_up(incl, off);
        if (lane >= off) incl += t2;
      }
      const int wtot = __shfl(incl, 63);
      if (!pushed) {
        if (wtot == 0) {
          pushed = true;
        } else {
          int wbase = 0;
          if (lane == 63) {
            wbase = atomicAdd(&cnt_sh, wtot);
            if (wbase + wtot > CAP) { atomicAdd(&cnt_sh, -wtot); wbase = -1; ovf = 1; }
          }
          wbase = __shfl(wbase, 63);
          if (wbase >= 0) {
            int sl = wbase + incl - nloc;
            for (int i = 0; i < 4; ++i)
              for (int j = 0; j < 4; ++j) {
                const int rr = ry + 16 * i, cc = cy + 16 * j;
                if (rr < nrows && cc < ncols) {
                  const float s = acc[i][j] * 0.125f;
                  if (s >= th) {
                    cval[sl] = s;
                    cidx[sl] = spos_r[rr] * SL + spos_c[cc];
                    ++sl;
                  }
                }
              }
            pushed = true;
          }
        }
      }
      __syncthreads();
      if (ovf == 0) break;
      // ---- compaction (cold path): bitonic-sort fp32 buffer, raise thresh ----
      {
        const int n = cnt_sh;
        for (int j = n + tid; j < CAP; j += 256) { cval[j] = -FLT_MAX; cidx[j] = INT_MAX; }
        __syncthreads();
        for (int k2 = 2; k2 <= CAP; k2 <<= 1)
          for (int j2 = k2 >> 1; j2 >= 1; j2 >>= 1) {
            const int i = ((tid & ~(j2 - 1)) << 1) | (tid & (j2 - 1));
            const int p = i | j2;
            const bool desc = ((i & k2) == 0);
            const float vi = cval[i], vp = cval[p];
            const int ii = cidx[i], ip = cidx[p];
            const bool sw = desc ? cgt32(vp, ip, vi, ii) : cgt32(vi, ii, vp, ip);
            if (sw) { cval[i] = vp; cidx[i] = ip; cval[p] = vi; cidx[p] = ii; }
            __syncthreads();
          }
        const float t64 = cval[KK - 1];
        const float nth = (t64 > -FLT_MAX) ? (t64 - MARGIN) : thresh;
        for (int j = tid; j < CAP; j += 256) {
          const bool in = (cidx[j] != INT_MAX) && (cval[j] >= nth);
          const bool nx = (j + 1 < CAP) && (cidx[j + 1] != INT_MAX) && (cval[j + 1] >= nth);
          if (in && !nx) mcnt = j + 1;
          if (j == 0 && !in) mcnt = 0;
        }
        __syncthreads();
        if (tid == 0) { thresh = nth; cnt_sh = mcnt; ovf = 0; }
        __syncthreads();
      }
    }
    __syncthreads();  // protect sK/spos_c restage
  }

  // ---- fp64 refine + exact bitonic-512 sort + top-64 out ----
  const int n = cnt_sh;
  double* rval = (double*)sQ;  // alias: sQ dead after scoring
  for (int j = tid; j < CAP; j += 256) {
    if (j < n) {
      const int fi = cidx[j];
      const int orow = fi >> 11, ocol = fi & (SL - 1);
      const float* qr = Q + ((size_t)b * SL + orow) * PP;
      const float* kr = K + ((size_t)b * SL + ocol) * PP;
      double a0 = 0, a1 = 0, a2 = 0, a3 = 0;
#pragma unroll 4
      for (int p = 0; p < PP; p += 4) {
        a0 = fma((double)qr[p], (double)kr[p], a0);
        a1 = fma((double)qr[p + 1], (double)kr[p + 1], a1);
        a2 = fma((double)qr[p + 2], (double)kr[p + 2], a2);
        a3 = fma((double)qr[p + 3], (double)kr[p + 3], a3);
      }
      rval[j] = ((a0 + a1) + (a2 + a3)) * 0.125;
    } else {
      rval[j] = -DBL_MAX;
      cidx[j] = INT_MAX;
    }
  }
  __syncthreads();
  for (int k2 = 2; k2 <= CAP; k2 <<= 1)
    for (int j2 = k2 >> 1; j2 >= 1; j2 >>= 1) {
      const int i = ((tid & ~(j2 - 1)) << 1) | (tid & (j2 - 1));
      const int p = i | j2;
      const bool desc = ((i & k2) == 0);
      const double vi = rval[i], vp = rval[p];
      const int ii = cidx[i], ip = cidx[p];
      const bool sw = desc ? cgt64(vp, ip, vi, ii) : cgt64(vi, ii, vp, ip);
      if (sw) { rval[i] = vp; cidx[i] = ip; rval[p] = vi; cidx[p] = ii; }
      __syncthreads();
    }
  if (tid < KK) { chv[tid] = rval[tid]; chi[tid] = cidx[tid]; }
}

// One block per batch: 256-way merge of sorted lists (heads staged in LDS),
// fp64 softmax, outputs.
__global__ __launch_bounds__(256) void merge_kernel(
    const double* __restrict__ chunk_val, const int* __restrict__ chunk_idx,
    float* __restrict__ out) {
  __shared__ double sval[NSLOT * 16];
  __shared__ int sidx[NSLOT * 16];
  const int b = blockIdx.x, tid = threadIdx.x;
  const double* vb = chunk_val + (size_t)b * NSLOT * KK;
  const int* ib = chunk_idx + (size_t)b * NSLOT * KK;
  for (int t = tid; t < NSLOT * 16; t += 256) {
    const int list = t >> 4, e = t & 15;
    sval[t] = vb[list * KK + e];
    sidx[t] = ib[list * KK + e];
  }
  __syncthreads();
  if (tid < 64) {
    const int lane = tid;
    double cur[4]; int curi[4]; int hp[4];
    for (int l = 0; l < 4; ++l) {
      const int list = lane * 4 + l;
      hp[l] = 0;
      cur[l] = sval[list * 16];
      curi[l] = sidx[list * 16];
    }
    double myv = -DBL_MAX; int myi = INT_MAX;
    for (int k = 0; k < KK; ++k) {
      double bv = cur[0]; int bi = curi[0]; int bl = 0;
      for (int l = 1; l < 4; ++l)
        if (cgt64(cur[l], curi[l], bv, bi)) { bv = cur[l]; bi = curi[l]; bl = l; }
      int bg = lane * 4 + bl;
      for (int off = 32; off > 0; off >>= 1) {
        const double v2 = __shfl_down(bv, off);
        const int i2 = __shfl_down(bi, off);
        const int g2 = __shfl_down(bg, off);
        if (cgt64(v2, i2, bv, bi)) { bv = v2; bi = i2; bg = g2; }
      }
      bv = __shfl(bv, 0); bi = __shfl(bi, 0); bg = __shfl(bg, 0);
      if ((bg >> 2) == lane) {
        const int l = bg & 3;
        const int h = ++hp[l];
        if (h < 16) { cur[l] = sval[bg * 16 + h]; curi[l] = sidx[bg * 16 + h]; }
        else if (h < KK) { cur[l] = vb[bg * KK + h]; curi[l] = ib[bg * KK + h]; }
        else { cur[l] = -DBL_MAX; curi[l] = INT_MAX; }
      }
      if (lane == k) { myv = bv; myi = bi; }
    }
    const double m = __shfl(myv, 0);
    double e = (myi == INT_MAX || myv == -DBL_MAX) ? 0.0 : exp(myv - m);
    double s = e;
    for (int off = 32; off > 0; off >>= 1) s += __shfl_down(s, off);
    s = __shfl(s, 0);
    if (s <= 0.0) s = 1.0;
    const double w = e / s;
    int row = 0, col = 0;
    if (myi != INT_MAX) { row = myi >> 11; col = myi & (SL - 1); }
    float* oidx = out;
    float* owt = out + (size_t)NB * KK * 2;
    oidx[((size_t)b * KK + lane) * 2 + 0] = (float)row;
    oidx[((size_t)b * KK + lane) * 2 + 1] = (float)col;
    owt[(size_t)b * KK + lane] = (float)w;
  }
}

}  // namespace

extern "C" void kernel_launch(void* const* d_in, const int* in_sizes, int n_in,
                              void* d_out, int out_size, void* d_ws, size_t ws_size,
                              hipStream_t stream) {
  const float* x = (const float*)d_in[0];
  const void* mask_raw = d_in[1];
  const float* Wq = (const float*)d_in[2];
  const float* bq = (const float*)d_in[3];
  const float* Wk = (const float*)d_in[4];
  const float* bk = (const float*)d_in[5];
  float* out = (float*)d_out;

  char* ws = (char*)d_ws;
  const size_t qk = (size_t)NB * SL * PP;  // 1,048,576 elems
  float* Q = (float*)ws;                                            // 4 MB
  float* K = (float*)(ws + qk * 4);                                 // 4 MB
  size_t off = qk * 8;
  double* chunk_val = (double*)(ws + off); off += (size_t)NB * NSLOT * KK * 8;  // 1 MB
  int* chunk_idx = (int*)(ws + off);       off += (size_t)NB * NSLOT * KK * 4;  // 512 KB
  int* pos = (int*)(ws + off);             off += (size_t)NB * SL * 4;          // 64 KB
  int* cntv = (int*)(ws + off);            off += 64;
  float* T0 = (float*)(ws + off);

  compact_kernel<<<NB, 256, 0, stream>>>(mask_raw, pos, cntv);
  proj_kernel<<<NB * SL / 8, 256, 0, stream>>>(x, Wq, bq, Wk, bk, Q, K);
  t0_kernel<<<NB, 256, 0, stream>>>(Q, K, pos, cntv, T0);
  score_kernel<<<dim3(NSTRIP, CSPLIT, NB), 256, 0, stream>>>(Q, K, pos, cntv, T0,
                                                             chunk_val, chunk_idx);
  merge_kernel<<<NB, 256, 0, stream>>>(chunk_val, chunk_idx, out);
}

// Round 6
// 307.680 us; speedup vs baseline: 1.5506x; 1.5506x over previous
//
#include <hip/hip_runtime.h>
#include <float.h>
#include <limits.h>
#include <math.h>

namespace {

constexpr int NB = 8;
constexpr int SL = 2048;
constexpr int DIM = 128;
constexpr int PP = 64;
constexpr int KK = 64;
constexpr int ROWS = 64;
constexpr int CTILE = 64;
constexpr int NSTRIP = SL / ROWS;        // 32
constexpr int CSPLIT = 8;
constexpr int NSLOT = NSTRIP * CSPLIT;   // 256 slots per batch
constexpr int CAP = 512;                 // candidate buffer (expected ~21/block)
constexpr float MARGIN = 4e-3f;          // >> 40x worst-case fp32 dot error

__device__ __forceinline__ bool cgt64(double v1, int i1, double v2, int i2) {
  return (v1 > v2) || (v1 == v2 && i1 < i2);
}
__device__ __forceinline__ bool cgt32(float v1, int i1, float v2, int i2) {
  return (v1 > v2) || (v1 == v2 && i1 < i2);
}

// Canonicalize mask (int32 words or raw bytes) + per-batch compaction.
__global__ __launch_bounds__(256) void compact_kernel(
    const void* __restrict__ mask_raw, int* __restrict__ pos, int* __restrict__ cnt) {
  const int b = blockIdx.x;
  const int tid = threadIdx.x;
  const int lane = tid & 63, wid = tid >> 6;
  __shared__ int bytemode;
  __shared__ int wsum[4];
  if (tid == 0) bytemode = 0;
  __syncthreads();
  const unsigned char* allb = (const unsigned char*)mask_raw;
  // dtype probe on first 512 bytes: int32-bool has zero at every t%4!=0
  int local = 0;
  for (int t = tid; t < 512; t += 256)
    if ((t & 3) != 0 && allb[t] != 0) local = 1;
  if (local) atomicOr(&bytemode, 1);
  __syncthreads();
  int f[8]; int c = 0;
  const int base = tid * 8;
  if (bytemode) {
    const unsigned char* p = allb + (size_t)b * SL;
    for (int j = 0; j < 8; ++j) { f[j] = p[base + j] ? 1 : 0; c += f[j]; }
  } else {
    const int* p = (const int*)mask_raw + (size_t)b * SL;
    for (int j = 0; j < 8; ++j) { f[j] = p[base + j] ? 1 : 0; c += f[j]; }
  }
  int incl = c;
  for (int off = 1; off < 64; off <<= 1) {
    int t = __shfl_up(incl, off);
    if (lane >= off) incl += t;
  }
  if (lane == 63) wsum[wid] = incl;
  __syncthreads();
  int woff = 0;
  for (int w = 0; w < wid; ++w) woff += wsum[w];
  int k = woff + incl - c;
  for (int j = 0; j < 8; ++j)
    if (f[j]) pos[b * SL + (k++)] = base + j;
  if (tid == 255) cnt[b] = k;
}

// Q = x@Wq+bq, K = x@Wk+bk. fp64 accumulation (8 indep chains), fp32 store.
__global__ __launch_bounds__(256) void proj_kernel(
    const float* __restrict__ x,
    const float* __restrict__ Wq, const float* __restrict__ bq,
    const float* __restrict__ Wk, const float* __restrict__ bk,
    float* __restrict__ Q, float* __restrict__ K) {
  __shared__ float sx[8 * DIM];
  const int row0 = blockIdx.x * 8;
  const int tid = threadIdx.x;
  for (int t = tid; t < 8 * DIM; t += 256) sx[t] = x[(size_t)row0 * DIM + t];
  __syncthreads();
  const int r = tid >> 5;
  const int pp = (tid & 31) * 2;
  double aq0 = 0, aq1 = 0, ak0 = 0, ak1 = 0;
  double cq0 = 0, cq1 = 0, ck0 = 0, ck1 = 0;
  const float* xr = &sx[r * DIM];
  for (int d = 0; d < DIM; d += 2) {
    const double x0 = (double)xr[d], x1 = (double)xr[d + 1];
    const float2 wq0 = *(const float2*)&Wq[d * PP + pp];
    const float2 wq1 = *(const float2*)&Wq[(d + 1) * PP + pp];
    const float2 wk0 = *(const float2*)&Wk[d * PP + pp];
    const float2 wk1 = *(const float2*)&Wk[(d + 1) * PP + pp];
    aq0 += x0 * (double)wq0.x; aq1 += x0 * (double)wq0.y;
    cq0 += x1 * (double)wq1.x; cq1 += x1 * (double)wq1.y;
    ak0 += x0 * (double)wk0.x; ak1 += x0 * (double)wk0.y;
    ck0 += x1 * (double)wk1.x; ck1 += x1 * (double)wk1.y;
  }
  const size_t o = ((size_t)row0 + r) * PP + pp;
  Q[o]     = (float)(aq0 + cq0 + (double)bq[pp]);
  Q[o + 1] = (float)(aq1 + cq1 + (double)bq[pp + 1]);
  K[o]     = (float)(ak0 + ck0 + (double)bk[pp]);
  K[o + 1] = (float)(ak1 + ck1 + (double)bk[pp + 1]);
}

// Safe threshold: 64th of 256 per-thread maxima over 128x128-valid subset.
__global__ __launch_bounds__(256) void t0_kernel(
    const float* __restrict__ Q, const float* __restrict__ K,
    const int* __restrict__ pos, const int* __restrict__ cnt,
    float* __restrict__ T0) {
  __shared__ __align__(16) float sq[128 * 68];
  __shared__ __align__(16) float sk[128 * 68];
  __shared__ float smax[256];
  const int b = blockIdx.x;
  const int tid = threadIdx.x;
  const int nv = cnt[b];
  const int nr = nv < 128 ? nv : 128;
  for (int t = tid; t < 128 * 16; t += 256) {
    const int row = t >> 4, p4 = t & 15;
    float4 qv = make_float4(0.f, 0.f, 0.f, 0.f), kv = qv;
    if (row < nr) {
      const int g = pos[b * SL + row];
      qv = *(const float4*)(Q + ((size_t)b * SL + g) * PP + p4 * 4);
      kv = *(const float4*)(K + ((size_t)b * SL + g) * PP + p4 * 4);
    }
    *(float4*)&sq[row * 68 + p4 * 4] = qv;
    *(float4*)&sk[row * 68 + p4 * 4] = kv;
  }
  __syncthreads();
  const int ry = tid & 15, cy = tid >> 4;
  float lmax = -FLT_MAX;
  // process in 4 row-groups of 2 to keep register pressure low
  for (int ih = 0; ih < 4; ++ih) {
    float acc[2][8] = {};
    for (int p4 = 0; p4 < 16; ++p4) {
      float4 qv[2], kv[8];
#pragma unroll
      for (int i = 0; i < 2; ++i)
        qv[i] = *(const float4*)&sq[(ry + 16 * (ih * 2 + i)) * 68 + p4 * 4];
#pragma unroll
      for (int j = 0; j < 8; ++j) kv[j] = *(const float4*)&sk[(cy + 16 * j) * 68 + p4 * 4];
#pragma unroll
      for (int i = 0; i < 2; ++i)
#pragma unroll
        for (int j = 0; j < 8; ++j) {
          acc[i][j] = fmaf(qv[i].x, kv[j].x, acc[i][j]);
          acc[i][j] = fmaf(qv[i].y, kv[j].y, acc[i][j]);
          acc[i][j] = fmaf(qv[i].z, kv[j].z, acc[i][j]);
          acc[i][j] = fmaf(qv[i].w, kv[j].w, acc[i][j]);
        }
    }
    for (int i = 0; i < 2; ++i)
      for (int j = 0; j < 8; ++j)
        if ((ry + 16 * (ih * 2 + i)) < nr && (cy + 16 * j) < nr)
          lmax = fmaxf(lmax, acc[i][j] * 0.125f);
  }
  smax[tid] = lmax;
  __syncthreads();
  // bitonic-256 descending on values
  for (int k2 = 2; k2 <= 256; k2 <<= 1)
    for (int j2 = k2 >> 1; j2 >= 1; j2 >>= 1) {
      if (tid < 128) {
        const int i = ((tid & ~(j2 - 1)) << 1) | (tid & (j2 - 1));
        const int p = i | j2;
        const bool desc = ((i & k2) == 0);
        const float vi = smax[i], vp = smax[p];
        const bool sw = desc ? (vp > vi) : (vi > vp);
        if (sw) { smax[i] = vp; smax[p] = vi; }
      }
      __syncthreads();
    }
  if (tid == 0) T0[b] = (smax[KK - 1] > -FLT_MAX) ? smax[KK - 1] - MARGIN : -FLT_MAX;
}

// Per (batch, 64-row strip, col eighth): fp32 scores with conflict-free
// 4x4 strided micro-tile, wave-granular thresholded emission, fp64 refine,
// adaptive bitonic exact sort, top-64 out (sorted desc by (val, idx)).
// __launch_bounds__(256, 2): VGPR cap 256 — R4's (256,4) forced 64 VGPRs and
// spilled ~680 MB/launch to scratch (FETCH 247 MB, WRITE 429 MB). LDS (40 KB)
// caps residency at 4 blocks/CU regardless.
__global__ __launch_bounds__(256, 2) void score_kernel(
    const float* __restrict__ Q, const float* __restrict__ K,
    const int* __restrict__ pos, const int* __restrict__ cnt,
    const float* __restrict__ T0,
    double* __restrict__ chunk_val, int* __restrict__ chunk_idx) {
  __shared__ __align__(16) float sQ[64 * 68];   // [row][17 float4] — aliased by rval later
  __shared__ __align__(16) float sK[64 * 68];
  __shared__ float cval[CAP];
  __shared__ int cidx[CAP];
  __shared__ int spos_r[ROWS], spos_c[CTILE];
  __shared__ int cnt_sh, ovf, mcnt;
  __shared__ float thresh;

  const int b = blockIdx.z, strip = blockIdx.x, colq = blockIdx.y;
  const int tid = threadIdx.x, lane = tid & 63;
  const int nv = cnt[b];
  const int slot = (b * NSTRIP + strip) * CSPLIT + colq;
  const int r0 = strip * ROWS;
  const int per = (nv + CSPLIT - 1) / CSPLIT;
  const int cbeg = colq * per;
  const int cend = min(cbeg + per, nv);
  double* chv = chunk_val + (size_t)slot * KK;
  int* chi = chunk_idx + (size_t)slot * KK;
  if (r0 >= nv || cbeg >= cend) {
    if (tid < KK) { chv[tid] = -DBL_MAX; chi[tid] = INT_MAX; }
    return;
  }
  const int nrows = min(ROWS, nv - r0);
  if (tid < ROWS) spos_r[tid] = (tid < nrows) ? pos[b * SL + r0 + tid] : 0;
  for (int t = tid; t < 64 * 16; t += 256) {
    const int row = t >> 4, p4 = t & 15;
    float4 v = make_float4(0.f, 0.f, 0.f, 0.f);
    if (row < nrows) {
      const int g = pos[b * SL + r0 + row];
      v = *(const float4*)(Q + ((size_t)b * SL + g) * PP + p4 * 4);
    }
    *(float4*)&sQ[row * 68 + p4 * 4] = v;
  }
  if (tid == 0) { cnt_sh = 0; ovf = 0; thresh = T0[b]; }
  __syncthreads();

  const int ry = tid & 15, cy = tid >> 4;   // rows ry+16i, cols cy+16j

  for (int c0 = cbeg; c0 < cend; c0 += CTILE) {
    const int ncols = min(CTILE, cend - c0);
    if (tid < CTILE) spos_c[tid] = (tid < ncols) ? pos[b * SL + c0 + tid] : 0;
    for (int t = tid; t < 64 * 16; t += 256) {
      const int col = t >> 4, p4 = t & 15;
      float4 v = make_float4(0.f, 0.f, 0.f, 0.f);
      if (col < ncols) {
        const int g = pos[b * SL + c0 + col];
        v = *(const float4*)(K + ((size_t)b * SL + g) * PP + p4 * 4);
      }
      *(float4*)&sK[col * 68 + p4 * 4] = v;
    }
    __syncthreads();

    float acc[4][4] = {};
#pragma unroll
    for (int p4 = 0; p4 < 16; ++p4) {
      float4 qv[4], kv[4];
#pragma unroll
      for (int i = 0; i < 4; ++i) qv[i] = *(const float4*)&sQ[(ry + 16 * i) * 68 + p4 * 4];
#pragma unroll
      for (int j = 0; j < 4; ++j) kv[j] = *(const float4*)&sK[(cy + 16 * j) * 68 + p4 * 4];
#pragma unroll
      for (int i = 0; i < 4; ++i)
#pragma unroll
        for (int j = 0; j < 4; ++j) {
          acc[i][j] = fmaf(qv[i].x, kv[j].x, acc[i][j]);
          acc[i][j] = fmaf(qv[i].y, kv[j].y, acc[i][j]);
          acc[i][j] = fmaf(qv[i].z, kv[j].z, acc[i][j]);
          acc[i][j] = fmaf(qv[i].w, kv[j].w, acc[i][j]);
        }
    }

    // wave-granular all-or-nothing emission; overflow -> compact + retry
    bool pushed = false;
    for (int attempt = 0; attempt < 8; ++attempt) {
      const float th = thresh;
      int nloc = 0;
#pragma unroll
      for (int i = 0; i < 4; ++i)
#pragma unroll
        for (int j = 0; j < 4; ++j)
          if ((ry + 16 * i) < nrows && (cy + 16 * j) < ncols &&
              acc[i][j] * 0.125f >= th)
            nloc++;
      int incl = nloc;
      for (int off = 1; off < 64; off <<= 1) {
        int t2 = __shfl_up(incl, off);
        if (lane >= off) incl += t2;
      }
      const int wtot = __shfl(incl, 63);
      if (!pushed) {
        if (wtot == 0) {
          pushed = true;
        } else {
          int wbase = 0;
          if (lane == 63) {
            wbase = atomicAdd(&cnt_sh, wtot);
            if (wbase + wtot > CAP) { atomicAdd(&cnt_sh, -wtot); wbase = -1; ovf = 1; }
          }
          wbase = __shfl(wbase, 63);
          if (wbase >= 0) {
            int sl = wbase + incl - nloc;
            for (int i = 0; i < 4; ++i)
              for (int j = 0; j < 4; ++j) {
                const int rr = ry + 16 * i, cc = cy + 16 * j;
                if (rr < nrows && cc < ncols) {
                  const float s = acc[i][j] * 0.125f;
                  if (s >= th) {
                    cval[sl] = s;
                    cidx[sl] = spos_r[rr] * SL + spos_c[cc];
                    ++sl;
                  }
                }
              }
            pushed = true;
          }
        }
      }
      __syncthreads();
      if (ovf == 0) break;
      // ---- compaction (cold path): bitonic-sort fp32 buffer, raise thresh ----
      {
        const int n = cnt_sh;
        for (int j = n + tid; j < CAP; j += 256) { cval[j] = -FLT_MAX; cidx[j] = INT_MAX; }
        __syncthreads();
        for (int k2 = 2; k2 <= CAP; k2 <<= 1)
          for (int j2 = k2 >> 1; j2 >= 1; j2 >>= 1) {
            const int i = ((tid & ~(j2 - 1)) << 1) | (tid & (j2 - 1));
            const int p = i | j2;
            const bool desc = ((i & k2) == 0);
            const float vi = cval[i], vp = cval[p];
            const int ii = cidx[i], ip = cidx[p];
            const bool sw = desc ? cgt32(vp, ip, vi, ii) : cgt32(vi, ii, vp, ip);
            if (sw) { cval[i] = vp; cidx[i] = ip; cval[p] = vi; cidx[p] = ii; }
            __syncthreads();
          }
        const float t64 = cval[KK - 1];
        const float nth = (t64 > -FLT_MAX) ? (t64 - MARGIN) : thresh;
        for (int j = tid; j < CAP; j += 256) {
          const bool in = (cidx[j] != INT_MAX) && (cval[j] >= nth);
          const bool nx = (j + 1 < CAP) && (cidx[j + 1] != INT_MAX) && (cval[j + 1] >= nth);
          if (in && !nx) mcnt = j + 1;
          if (j == 0 && !in) mcnt = 0;
        }
        __syncthreads();
        if (tid == 0) { thresh = nth; cnt_sh = mcnt; ovf = 0; }
        __syncthreads();
      }
    }
    __syncthreads();  // protect sK/spos_c restage
  }

  // ---- fp64 refine + adaptive exact bitonic sort + top-64 out ----
  const int n = cnt_sh;
  int np2 = KK;
  while (np2 < n) np2 <<= 1;  // n <= CAP
  double* rval = (double*)sQ;  // alias: sQ dead after scoring
  for (int j = tid; j < np2; j += 256) {
    if (j < n) {
      const int fi = cidx[j];
      const int orow = fi >> 11, ocol = fi & (SL - 1);
      const float* qr = Q + ((size_t)b * SL + orow) * PP;
      const float* kr = K + ((size_t)b * SL + ocol) * PP;
      double a0 = 0, a1 = 0, a2 = 0, a3 = 0;
#pragma unroll 4
      for (int p = 0; p < PP; p += 4) {
        a0 = fma((double)qr[p], (double)kr[p], a0);
        a1 = fma((double)qr[p + 1], (double)kr[p + 1], a1);
        a2 = fma((double)qr[p + 2], (double)kr[p + 2], a2);
        a3 = fma((double)qr[p + 3], (double)kr[p + 3], a3);
      }
      rval[j] = ((a0 + a1) + (a2 + a3)) * 0.125;
    } else {
      rval[j] = -DBL_MAX;
      cidx[j] = INT_MAX;
    }
  }
  __syncthreads();
  for (int k2 = 2; k2 <= np2; k2 <<= 1)
    for (int j2 = k2 >> 1; j2 >= 1; j2 >>= 1) {
      if (tid < (np2 >> 1)) {
        const int i = ((tid & ~(j2 - 1)) << 1) | (tid & (j2 - 1));
        const int p = i | j2;
        const bool desc = ((i & k2) == 0);
        const double vi = rval[i], vp = rval[p];
        const int ii = cidx[i], ip = cidx[p];
        const bool sw = desc ? cgt64(vp, ip, vi, ii) : cgt64(vi, ii, vp, ip);
        if (sw) { rval[i] = vp; cidx[i] = ip; rval[p] = vi; cidx[p] = ii; }
      }
      __syncthreads();
    }
  if (tid < KK) { chv[tid] = rval[tid]; chi[tid] = cidx[tid]; }
}

// One block per batch: 256-way merge of sorted lists (heads staged in LDS),
// fp64 softmax, outputs.
__global__ __launch_bounds__(256) void merge_kernel(
    const double* __restrict__ chunk_val, const int* __restrict__ chunk_idx,
    float* __restrict__ out) {
  __shared__ double sval[NSLOT * 16];
  __shared__ int sidx[NSLOT * 16];
  const int b = blockIdx.x, tid = threadIdx.x;
  const double* vb = chunk_val + (size_t)b * NSLOT * KK;
  const int* ib = chunk_idx + (size_t)b * NSLOT * KK;
  for (int t = tid; t < NSLOT * 16; t += 256) {
    const int list = t >> 4, e = t & 15;
    sval[t] = vb[list * KK + e];
    sidx[t] = ib[list * KK + e];
  }
  __syncthreads();
  if (tid < 64) {
    const int lane = tid;
    double cur[4]; int curi[4]; int hp[4];
    for (int l = 0; l < 4; ++l) {
      const int list = lane * 4 + l;
      hp[l] = 0;
      cur[l] = sval[list * 16];
      curi[l] = sidx[list * 16];
    }
    double myv = -DBL_MAX; int myi = INT_MAX;
    for (int k = 0; k < KK; ++k) {
      double bv = cur[0]; int bi = curi[0]; int bl = 0;
      for (int l = 1; l < 4; ++l)
        if (cgt64(cur[l], curi[l], bv, bi)) { bv = cur[l]; bi = curi[l]; bl = l; }
      int bg = lane * 4 + bl;
      for (int off = 32; off > 0; off >>= 1) {
        const double v2 = __shfl_down(bv, off);
        const int i2 = __shfl_down(bi, off);
        const int g2 = __shfl_down(bg, off);
        if (cgt64(v2, i2, bv, bi)) { bv = v2; bi = i2; bg = g2; }
      }
      bv = __shfl(bv, 0); bi = __shfl(bi, 0); bg = __shfl(bg, 0);
      if ((bg >> 2) == lane) {
        const int l = bg & 3;
        const int h = ++hp[l];
        if (h < 16) { cur[l] = sval[bg * 16 + h]; curi[l] = sidx[bg * 16 + h]; }
        else if (h < KK) { cur[l] = vb[bg * KK + h]; curi[l] = ib[bg * KK + h]; }
        else { cur[l] = -DBL_MAX; curi[l] = INT_MAX; }
      }
      if (lane == k) { myv = bv; myi = bi; }
    }
    const double m = __shfl(myv, 0);
    double e = (myi == INT_MAX || myv == -DBL_MAX) ? 0.0 : exp(myv - m);
    double s = e;
    for (int off = 32; off > 0; off >>= 1) s += __shfl_down(s, off);
    s = __shfl(s, 0);
    if (s <= 0.0) s = 1.0;
    const double w = e / s;
    int row = 0, col = 0;
    if (myi != INT_MAX) { row = myi >> 11; col = myi & (SL - 1); }
    float* oidx = out;
    float* owt = out + (size_t)NB * KK * 2;
    oidx[((size_t)b * KK + lane) * 2 + 0] = (float)row;
    oidx[((size_t)b * KK + lane) * 2 + 1] = (float)col;
    owt[(size_t)b * KK + lane] = (float)w;
  }
}

}  // namespace

extern "C" void kernel_launch(void* const* d_in, const int* in_sizes, int n_in,
                              void* d_out, int out_size, void* d_ws, size_t ws_size,
                              hipStream_t stream) {
  const float* x = (const float*)d_in[0];
  const void* mask_raw = d_in[1];
  const float* Wq = (const float*)d_in[2];
  const float* bq = (const float*)d_in[3];
  const float* Wk = (const float*)d_in[4];
  const float* bk = (const float*)d_in[5];
  float* out = (float*)d_out;

  char* ws = (char*)d_ws;
  const size_t qk = (size_t)NB * SL * PP;  // 1,048,576 elems
  float* Q = (float*)ws;                                            // 4 MB
  float* K = (float*)(ws + qk * 4);                                 // 4 MB
  size_t off = qk * 8;
  double* chunk_val = (double*)(ws + off); off += (size_t)NB * NSLOT * KK * 8;  // 1 MB
  int* chunk_idx = (int*)(ws + off);       off += (size_t)NB * NSLOT * KK * 4;  // 512 KB
  int* pos = (int*)(ws + off);             off += (size_t)NB * SL * 4;          // 64 KB
  int* cntv = (int*)(ws + off);            off += 64;
  float* T0 = (float*)(ws + off);

  compact_kernel<<<NB, 256, 0, stream>>>(mask_raw, pos, cntv);
  proj_kernel<<<NB * SL / 8, 256, 0, stream>>>(x, Wq, bq, Wk, bk, Q, K);
  t0_kernel<<<NB, 256, 0, stream>>>(Q, K, pos, cntv, T0);
  score_kernel<<<dim3(NSTRIP, CSPLIT, NB), 256, 0, stream>>>(Q, K, pos, cntv, T0,
                                                             chunk_val, chunk_idx);
  merge_kernel<<<NB, 256, 0, stream>>>(chunk_val, chunk_idx, out);
}